// Round 23
// baseline (278.192 us; speedup 1.0000x reference)
//
#include <hip/hip_runtime.h>
#include <cmath>

typedef unsigned short ushort_t;
typedef unsigned int u32;
typedef __attribute__((ext_vector_type(8))) __bf16 bf16x8;
typedef __attribute__((ext_vector_type(4))) float f32x4;

#define Hh 16
#define Ss 2048
#define SCALE 0.08838834764831845f

__device__ __forceinline__ ushort_t f2bf(float f) {
  union { float f; unsigned u; } c; c.f = f;
  unsigned u = c.u;
  return (ushort_t)((u + 0x7FFFu + ((u >> 16) & 1u)) >> 16);  // RNE
}
__device__ __forceinline__ float bf2f(ushort_t h) {
  union { unsigned u; float f; } c; c.u = ((unsigned)h) << 16;
  return c.f;
}
// pack 2 f32 -> 2 bf16 in one dword (lo->low16, hi->high16)
__device__ __forceinline__ u32 cvt_pk_bf16(float lo, float hi) {
  u32 r;
  asm volatile("v_cvt_pk_bf16_f32 %0, %1, %2" : "=v"(r) : "v"(lo), "v"(hi));
  return r;
}

// async global->LDS 16B (wave-uniform LDS base + lane*16B dest; per-lane gsrc)
__device__ __forceinline__ void gload_lds16(const ushort_t* g, ushort_t* l) {
  __builtin_amdgcn_global_load_lds(
      (const __attribute__((address_space(1))) u32*)g,
      (__attribute__((address_space(3))) u32*)l, 16, 0, 0);
}

// ---------------------------------------------------------------------------
// One-shot setup: segments 0..8 fp32->bf16 (x + 8 weights), 9..15 bias
// copies (fp32), 16 rope cos/sin table (65536 entries).
// ---------------------------------------------------------------------------
struct SrcPtrs { const float* p[16]; };

__global__ __launch_bounds__(256) void convert_all_kernel(SrcPtrs sp,
    ushort_t* __restrict__ x_bf, ushort_t* __restrict__ wbuf,
    float* __restrict__ biasbuf, float2* __restrict__ ropetb) {
  const int cum[16] = {8192, 9216, 10240, 12288, 12800, 13824, 14336, 14848,
                       18944, 18945, 18946, 18947, 18948, 18950, 18951, 18952};
  const int dsto[9] = {0, 0, 1048576, 2097152, 4194304, 4718592, 5767168, 6291456, 6815744};
  const int boff[7] = {0, 512, 1024, 2048, 3072, 5120, 6144};
  const int bsz[7]  = {512, 512, 1024, 1024, 2048, 1024, 1024};
  const int bid = blockIdx.x;
  int s = 0;
  #pragma unroll
  for (int i = 0; i < 16; ++i) s += (bid >= cum[i]);
  const int lb = bid - (s == 0 ? 0 : cum[s - 1]);
  if (s < 9) {
    const float* src = sp.p[s] + (size_t)lb * 1024;
    ushort_t* dst = (s == 0 ? x_bf : wbuf + dsto[s]) + (size_t)lb * 1024;
    const int i = threadIdx.x * 4;
    float4 v = *(const float4*)&src[i];
    ushort4 o;
    o.x = f2bf(v.x); o.y = f2bf(v.y); o.z = f2bf(v.z); o.w = f2bf(v.w);
    *(ushort4*)&dst[i] = o;
  } else if (s < 16) {
    const int k = s - 9;
    const int e = lb * 1024 + threadIdx.x * 4;
    if (e < bsz[k])
      *(float4*)&biasbuf[boff[k] + e] = *(const float4*)&sp.p[s][e];
  } else {
    const int i = lb * 256 + threadIdx.x;          // 65536 entries
    const int sq = i >> 5, ii = i & 31;
    const float invf = expf(-logf(10000.f) * (float)ii / 32.f);
    const float fr = (float)sq * invf;
    ropetb[i] = make_float2(cosf(fr), sinf(fr));
  }
}

// ---------------------------------------------------------------------------
// Narrow-tile bf16 MFMA GEMM: 128m x 64n tile, BK=64, 4 waves stacked along
// m (wave w owns rows w*32..w*32+31, ALL 64 cols). acc[2][4] = 32 regs/thr
// (half of the 128x128 kernel) -> ~110 total regs -> 4 blocks/CU (was 2).
// Per-output FP sequence identical to the wide kernel (same BK/dk/k0 order).
// MODE 0: out-proj fp32: addr = m*2048 + n          (grid 32x32)
// MODE 2: x-fused (N=2048): bx<16 -> kv_d/q_d (C0); bx>=16 -> kr+RoPE (C1)
//         64-wide n-tile aligns to one head's rope block; thread holds both
//         rotation-pair elements (frags p and p+2).
// ---------------------------------------------------------------------------
template<int MODE, typename OUTT>
__global__ __launch_bounds__(256) void gemm_bf16_n64(
    const ushort_t* __restrict__ A, const ushort_t* __restrict__ W,
    const float* __restrict__ bias, OUTT* __restrict__ C0,
    ushort_t* __restrict__ C1, const float2* __restrict__ tb, int K)
{
  __shared__ ushort_t As[128][64];   // 16 KB
  __shared__ ushort_t Bs[64][64];    //  8 KB
  const int tid = threadIdx.x;
  const int lane = tid & 63;
  const int w = tid >> 6;
  const int l15 = lane & 15, lhi = lane >> 4;
  const int m0 = blockIdx.y * 128, n0 = blockIdx.x * 64;

  const int srow = (lane >> 3);        // 0..7 within wave's 8-row stripe
  const int scol = (lane & 7) * 8;

  f32x4 acc[2][4];
  #pragma unroll
  for (int i = 0; i < 2; ++i)
    #pragma unroll
    for (int j = 0; j < 4; ++j)
      acc[i][j] = (f32x4){0.f, 0.f, 0.f, 0.f};

  for (int k0 = 0; k0 < K; k0 += 64) {
    __syncthreads();
    // A: 128 rows x 64 cols = 1024 chunks, 4 shots; wave w covers rows
    // q*32 + w*8 .. +8 each shot (wave-uniform LDS base + lane*16B).
    #pragma unroll
    for (int q = 0; q < 4; ++q) {
      const int row = q * 32 + w * 8 + srow;
      gload_lds16(&A[(size_t)(m0 + row) * K + k0 + scol], &As[q * 32 + w * 8][0]);
    }
    // B: 64 rows -> 2 shots.
    #pragma unroll
    for (int q = 0; q < 2; ++q) {
      const int row = q * 32 + w * 8 + srow;
      gload_lds16(&W[(size_t)(n0 + row) * K + k0 + scol], &Bs[q * 32 + w * 8][0]);
    }
    __syncthreads();
    #pragma unroll
    for (int dk = 0; dk < 2; ++dk) {
      bf16x8 af[2], bfr[4];
      #pragma unroll
      for (int i = 0; i < 2; ++i)
        af[i] = *(const bf16x8*)&As[w * 32 + i * 16 + l15][dk * 32 + lhi * 8];
      #pragma unroll
      for (int j = 0; j < 4; ++j)
        bfr[j] = *(const bf16x8*)&Bs[j * 16 + l15][dk * 32 + lhi * 8];
      #pragma unroll
      for (int i = 0; i < 2; ++i)
        #pragma unroll
        for (int j = 0; j < 4; ++j)
          acc[i][j] = __builtin_amdgcn_mfma_f32_16x16x32_bf16(af[i], bfr[j], acc[i][j], 0, 0, 0);
    }
  }

  if (MODE == 2 && blockIdx.x >= 16) {
    // rope region: n-tile covers one head's 64-wide rope block
    #pragma unroll
    for (int i = 0; i < 2; ++i) {
      #pragma unroll
      for (int p = 0; p < 2; ++p) {
        const int nA = n0 + p * 16 + l15;
        const int nB = nA + 32;
        const float bzA = bias[nA];
        const float bzB = bias[nB];
        const int npA = nA - 1024;
        const int colA = (npA >> 6) * 128 + (npA & 63);
        const int colB = colA + 32;
        const int ii = p * 16 + l15;
        #pragma unroll
        for (int r = 0; r < 4; ++r) {
          const int m = m0 + w * 32 + i * 16 + lhi * 4 + r;
          const int s = m & (Ss - 1);
          const float2 cs = tb[(s << 5) + ii];
          const float x1 = acc[i][p][r] + bzA;
          const float x2 = acc[i][p + 2][r] + bzB;
          C1[(size_t)m * 2048 + colA] = f2bf(x1 * cs.x - x2 * cs.y);
          C1[(size_t)m * 2048 + colB] = f2bf(x2 * cs.x + x1 * cs.y);
        }
      }
    }
    return;
  }

  #pragma unroll
  for (int i = 0; i < 2; ++i) {
    #pragma unroll
    for (int j = 0; j < 4; ++j) {
      const int n = n0 + j * 16 + l15;
      const float bz = bias[n];
      #pragma unroll
      for (int r = 0; r < 4; ++r) {
        const int m = m0 + w * 32 + i * 16 + lhi * 4 + r;
        const float v = acc[i][j][r] + bz;
        if constexpr (MODE == 0) {
          C0[(size_t)m * 2048 + n] = v;
        } else {  // MODE 2, bx<16: kv_d / q_d
          C0[(size_t)(n >> 9) * 2097152 + (size_t)m * 512 + (n & 511)] = (OUTT)f2bf(v);
        }
      }
    }
  }
}

// ---------------------------------------------------------------------------
// Wide bf16 MFMA GEMM (kvq-fused only; 5 blocks/CU already): 128x128 tile,
// BK=64, 4 waves. MODE 5: n<1024 -> kb (C0); <3072 -> vt (C1); <4096 -> qb
// q1 (C2); >=4096 -> qr+RoPE -> C2 (+64). A = kv_d for bx<24 else q_d.
// ---------------------------------------------------------------------------
template<int MODE, typename OUTT>
__global__ __launch_bounds__(256) void gemm_bf16(
    const ushort_t* __restrict__ A, const ushort_t* __restrict__ W,
    const float* __restrict__ bias, OUTT* __restrict__ C0,
    ushort_t* __restrict__ C1, ushort_t* __restrict__ C2,
    const float2* __restrict__ tb, int K)
{
  __shared__ ushort_t As[128][64];
  __shared__ ushort_t Bs[128][64];
  const int tid = threadIdx.x;
  const int lane = tid & 63;
  const int w = tid >> 6;
  const int wr = w >> 1, wc = w & 1;
  const int l15 = lane & 15, lhi = lane >> 4;
  const int m0 = blockIdx.y * 128, n0 = blockIdx.x * 128;

  if constexpr (MODE == 5) { if (blockIdx.x >= 24) A += 2097152; }

  const int srow_base = w * 8 + (lane >> 3);
  const int scol = (lane & 7) * 8;

  f32x4 acc[4][4];
  #pragma unroll
  for (int i = 0; i < 4; ++i)
    #pragma unroll
    for (int j = 0; j < 4; ++j)
      acc[i][j] = (f32x4){0.f, 0.f, 0.f, 0.f};

  for (int k0 = 0; k0 < K; k0 += 64) {
    __syncthreads();
    #pragma unroll
    for (int q = 0; q < 4; ++q) {
      const int row = q * 32 + srow_base;
      gload_lds16(&A[(size_t)(m0 + row) * K + k0 + scol], &As[q * 32 + w * 8][0]);
      gload_lds16(&W[(size_t)(n0 + row) * K + k0 + scol], &Bs[q * 32 + w * 8][0]);
    }
    __syncthreads();
    #pragma unroll
    for (int dk = 0; dk < 2; ++dk) {
      bf16x8 af[4], bfr[4];
      #pragma unroll
      for (int i = 0; i < 4; ++i)
        af[i] = *(const bf16x8*)&As[wr * 64 + i * 16 + l15][dk * 32 + lhi * 8];
      #pragma unroll
      for (int j = 0; j < 4; ++j)
        bfr[j] = *(const bf16x8*)&Bs[wc * 64 + j * 16 + l15][dk * 32 + lhi * 8];
      #pragma unroll
      for (int i = 0; i < 4; ++i)
        #pragma unroll
        for (int j = 0; j < 4; ++j)
          acc[i][j] = __builtin_amdgcn_mfma_f32_16x16x32_bf16(af[i], bfr[j], acc[i][j], 0, 0, 0);
    }
  }

  const bool rope_region = (MODE == 5 && blockIdx.x >= 32);

  if (rope_region) {
    #pragma unroll
    for (int i = 0; i < 4; ++i) {
      #pragma unroll
      for (int p = 0; p < 2; ++p) {
        const int nA = n0 + wc * 64 + p * 16 + l15;
        const int nB = nA + 32;
        const float bzA = bias[nA];
        const float bzB = bias[nB];
        const int npA = nA - 4096;
        const int colA = (npA >> 6) * 128 + 64 + (npA & 63);
        const int colB = colA + 32;
        const int ii = p * 16 + l15;
        #pragma unroll
        for (int r = 0; r < 4; ++r) {
          const int m = m0 + wr * 64 + i * 16 + lhi * 4 + r;
          const int s = m & (Ss - 1);
          const float2 cs = tb[(s << 5) + ii];
          const float x1 = acc[i][p][r] + bzA;
          const float x2 = acc[i][p + 2][r] + bzB;
          C2[(size_t)m * 2048 + colA] = f2bf(x1 * cs.x - x2 * cs.y);
          C2[(size_t)m * 2048 + colB] = f2bf(x2 * cs.x + x1 * cs.y);
        }
      }
    }
    return;
  }

  #pragma unroll
  for (int i = 0; i < 4; ++i) {
    #pragma unroll
    for (int j = 0; j < 4; ++j) {
      const int n = n0 + wc * 64 + j * 16 + l15;
      const float bz = bias[n];
      #pragma unroll
      for (int r = 0; r < 4; ++r) {
        const int m = m0 + wr * 64 + i * 16 + lhi * 4 + r;
        const float v = acc[i][j][r] + bz;
        if (n < 1024) {
          C0[(size_t)m * 2048 + (n >> 6) * 128 + (n & 63)] = (OUTT)f2bf(v);
        } else if (n < 3072) {
          const int np = n - 1024;
          C1[(size_t)(m >> 11) * 4194304 + (size_t)np * 2048 + (m & 2047)] = f2bf(v);
        } else {
          const int np = n - 3072;     // [0,1024): q1
          C2[(size_t)m * 2048 + (np >> 6) * 128 + (np & 63)] = f2bf(v);
        }
      }
    }
  }
}

// ---------------------------------------------------------------------------
// MFMA flash attention (R15/R18/R20/R22-proven optimum): XOR-swizzled 48KB
// LDS, lazy softmax, swapped QK^T, reg prefetch of t+1 under compute,
// XCD-grouped blocks (K/V L2-resident). 4 waves x 32 q-rows, KVBLK=64.
// Plateau: ~172 total regs => 2 blocks/CU structural (probed exhaustively).
// ---------------------------------------------------------------------------
__global__ __launch_bounds__(256) void flash_mfma_kernel(
    const ushort_t* __restrict__ Qb, const ushort_t* __restrict__ Kb,
    const ushort_t* __restrict__ Vt, ushort_t* __restrict__ Oattn)
{
  __shared__ ushort_t Ks[64][128];     // [kk][d], XOR-swizzled chunks
  __shared__ ushort_t Vs[128][64];     // [d][kk], XOR-swizzled
  __shared__ ushort_t Ps[4][32][64];   // per-wave P tile [q][kk], XOR-swizzled

  const int tid = threadIdx.x, lane = tid & 63, w = tid >> 6;
  const int l15 = lane & 15, lhi = lane >> 4;
  const int l7 = l15 & 7;
  // XCD-grouped decode: id = xcd + 8*((bh/8)*16 + qx)
  const int id = blockIdx.x;
  const int xcd = id & 7, chunk = id >> 3;
  const int qx = chunk & 15, bh = ((chunk >> 4) << 3) | xcd;
  const int b = bh >> 4, h = bh & 15;
  const int q0 = qx * 128 + w * 32;

  // Q fragments (B-operand of swapped QK^T)
  bf16x8 qf[2][4];
  #pragma unroll
  for (int mi = 0; mi < 2; ++mi) {
    const size_t qrow = (size_t)b * Ss + q0 + mi * 16 + l15;
    const ushort_t* qp = Qb + (qrow * Hh + h) * 128;
    #pragma unroll
    for (int dk = 0; dk < 4; ++dk)
      qf[mi][dk] = *(const bf16x8*)(qp + dk * 32 + lhi * 8);
  }

  f32x4 o[2][8];
  #pragma unroll
  for (int mi = 0; mi < 2; ++mi)
    #pragma unroll
    for (int dn = 0; dn < 8; ++dn) o[mi][dn] = (f32x4){0.f, 0.f, 0.f, 0.f};
  float lsum[2] = {0.f, 0.f};

  const size_t kbase_g = (size_t)b * Ss * 2048 + (size_t)h * 128;
  const size_t vbase_g = (size_t)bh * 128 * Ss;

  // staging regs: tile t+1 loaded right after barrier 2 (hides under compute)
  bf16x8 kv[4], vv[4];
  #pragma unroll
  for (int p = 0; p < 4; ++p) {
    const int idx = p * 256 + tid;
    kv[p] = *(const bf16x8*)&Kb[kbase_g + (size_t)(idx >> 4) * 2048 + (idx & 15) * 8];
    vv[p] = *(const bf16x8*)&Vt[vbase_g + (size_t)(idx >> 3) * Ss + (idx & 7) * 8];
  }

  for (int t = 0; t < Ss / 64; ++t) {
    __syncthreads();   // previous iter's LDS readers done
    #pragma unroll
    for (int p = 0; p < 4; ++p) {
      const int idx = p * 256 + tid;
      const int kr = idx >> 4, kc = idx & 15;
      const int vr = idx >> 3, vc = idx & 7;
      *(bf16x8*)&Ks[kr][(kc ^ (kr & 7)) * 8] = kv[p];
      *(bf16x8*)&Vs[vr][(vc ^ (vr & 7)) * 8] = vv[p];
    }
    __syncthreads();

    // prefetch tile t+1 into regs; returns while we compute tile t
    if (t + 1 < Ss / 64) {
      const int s1 = (t + 1) * 64;
      #pragma unroll
      for (int p = 0; p < 4; ++p) {
        const int idx = p * 256 + tid;
        kv[p] = *(const bf16x8*)&Kb[kbase_g + (size_t)(s1 + (idx >> 4)) * 2048 + (idx & 15) * 8];
        vv[p] = *(const bf16x8*)&Vt[vbase_g + (size_t)(idx >> 3) * Ss + s1 + (idx & 7) * 8];
      }
    }

    // swapped QK^T: lane -> q = l15, kk = jc*16 + lhi*4 + r
    f32x4 s[2][4];
    #pragma unroll
    for (int mi = 0; mi < 2; ++mi)
      #pragma unroll
      for (int jc = 0; jc < 4; ++jc) s[mi][jc] = (f32x4){0.f, 0.f, 0.f, 0.f};
    #pragma unroll
    for (int jc = 0; jc < 4; ++jc)
      #pragma unroll
      for (int dk = 0; dk < 4; ++dk) {
        bf16x8 ak = *(const bf16x8*)&Ks[jc * 16 + l15][((dk * 4 + lhi) ^ l7) * 8];
        s[0][jc] = __builtin_amdgcn_mfma_f32_16x16x32_bf16(ak, qf[0][dk], s[0][jc], 0, 0, 0);
        s[1][jc] = __builtin_amdgcn_mfma_f32_16x16x32_bf16(ak, qf[1][dk], s[1][jc], 0, 0, 0);
      }

    // lazy softmax: p = exp(S*scale); lane-local sum (q = l15); packed b64
    // P-writes into swizzled Ps (16B chunk = 2jc+(lhi>>1), 8B half = lhi&1)
    #pragma unroll
    for (int mi = 0; mi < 2; ++mi)
      #pragma unroll
      for (int jc = 0; jc < 4; ++jc) {
        const float p0 = __expf(s[mi][jc][0] * SCALE);
        const float p1 = __expf(s[mi][jc][1] * SCALE);
        const float p2 = __expf(s[mi][jc][2] * SCALE);
        const float p3 = __expf(s[mi][jc][3] * SCALE);
        lsum[mi] += (p0 + p1) + (p2 + p3);
        const u32 d0 = cvt_pk_bf16(p0, p1);
        const u32 d1 = cvt_pk_bf16(p2, p3);
        const int ch = (jc * 2 + (lhi >> 1)) ^ l7;
        *(uint2*)&Ps[w][mi * 16 + l15][ch * 8 + (lhi & 1) * 4] = make_uint2(d0, d1);
      }

    // PV: A = P (q x kk), B = V chunk from Vs[d][kk]; 2 k-chunks of 32
    #pragma unroll
    for (int kc = 0; kc < 2; ++kc) {
      bf16x8 ap0 = *(const bf16x8*)&Ps[w][l15][((kc * 4 + lhi) ^ l7) * 8];
      bf16x8 ap1 = *(const bf16x8*)&Ps[w][16 + l15][((kc * 4 + lhi) ^ l7) * 8];
      #pragma unroll
      for (int dn = 0; dn < 8; ++dn) {
        bf16x8 bv = *(const bf16x8*)&Vs[dn * 16 + l15][((kc * 4 + lhi) ^ l7) * 8];
        o[0][dn] = __builtin_amdgcn_mfma_f32_16x16x32_bf16(ap0, bv, o[0][dn], 0, 0, 0);
        o[1][dn] = __builtin_amdgcn_mfma_f32_16x16x32_bf16(ap1, bv, o[1][dn], 0, 0, 0);
      }
    }
  }

  // final row-sum reduce across lhi groups: all lanes get total for q = l15
  #pragma unroll
  for (int mi = 0; mi < 2; ++mi) {
    float v = lsum[mi];
    v += __shfl_xor(v, 16);
    v += __shfl_xor(v, 32);
    lsum[mi] = v;
  }

  // epilogue: normalize (row totals via shfl), write (b,s,h,128) bf16
  #pragma unroll
  for (int mi = 0; mi < 2; ++mi) {
    float inv[4];
    #pragma unroll
    for (int r = 0; r < 4; ++r)
      inv[r] = 1.f / __shfl(lsum[mi], lhi * 4 + r);
    #pragma unroll
    for (int dn = 0; dn < 8; ++dn)
      #pragma unroll
      for (int r = 0; r < 4; ++r) {
        const int row = q0 + mi * 16 + lhi * 4 + r;
        const size_t addr = ((size_t)b * Ss + row) * 2048 + h * 128 + dn * 16 + l15;
        Oattn[addr] = f2bf(o[mi][dn][r] * inv[r]);
      }
  }
}

// ---------------------------------------------------------------------------
extern "C" void kernel_launch(void* const* d_in, const int* in_sizes, int n_in,
                              void* d_out, int out_size, void* d_ws, size_t ws_size,
                              hipStream_t stream)
{
  const float* x     = (const float*)d_in[0];
  const float* Wkv_d = (const float*)d_in[1];
  const float* bkv_d = (const float*)d_in[2];
  const float* Wq_d  = (const float*)d_in[3];
  const float* bq_d  = (const float*)d_in[4];
  const float* Wk_u  = (const float*)d_in[5];
  const float* bk_u  = (const float*)d_in[6];
  const float* Wq_u  = (const float*)d_in[7];
  const float* bq_u  = (const float*)d_in[8];
  const float* Wv_u  = (const float*)d_in[9];
  const float* bv_u  = (const float*)d_in[10];
  const float* Wrk   = (const float*)d_in[11];
  const float* brk   = (const float*)d_in[12];
  const float* Wrq   = (const float*)d_in[13];
  const float* brq   = (const float*)d_in[14];
  const float* Wo    = (const float*)d_in[15];
  const float* bo    = (const float*)d_in[16];

  ushort_t* ws = (ushort_t*)d_ws;
  ushort_t* x_bf  = ws;                       // [0, 8388608)
  ushort_t* kv_d  = ws + 8388608;             // [4096][512]
  ushort_t* q_d   = ws + 10485760;            // [4096][512] = kv_d + 2097152
  ushort_t* qb    = ws + 12582912;            // (b,s,h,128)
  ushort_t* kb    = ws + 20971520;
  ushort_t* vt    = ws + 29360128;            // [b][h][d][s]
  ushort_t* attn  = ws + 37748736;
  ushort_t* wbuf  = ws + 46137344;            // bf16 weights (11,010,048)
  float* biasbuf  = (float*)(ws + 57147392);  // 7168 f32
  float2* ropetb  = (float2*)(ws + 57161728); // 65536 float2 = 512 KB

  SrcPtrs sp;
  sp.p[0] = x;     sp.p[1] = Wkv_d; sp.p[2] = Wq_d;  sp.p[3] = Wrk;
  sp.p[4] = Wk_u;  sp.p[5] = Wv_u;  sp.p[6] = Wq_u;  sp.p[7] = Wrq;
  sp.p[8] = Wo;
  sp.p[9] = bkv_d; sp.p[10] = bq_d; sp.p[11] = brk;  sp.p[12] = bk_u;
  sp.p[13] = bv_u; sp.p[14] = bq_u; sp.p[15] = brq;
  convert_all_kernel<<<dim3(19208), dim3(256), 0, stream>>>(sp, x_bf, wbuf, biasbuf, ropetb);

  const dim3 blk(256);

  // x-fused (narrow tile, 4 blocks/CU): kv_d, q_d (bx<16); kr+RoPE (bx>=16).
  gemm_bf16_n64<2, ushort_t><<<dim3(32, 32), blk, 0, stream>>>(
      x_bf, wbuf, biasbuf, kv_d, kb + 64, ropetb, 2048);
  // kvq-fused (wide tile, 5 blocks/CU): k1 -> kb, V -> vt, q1/qr -> qb.
  gemm_bf16<5, ushort_t><<<dim3(40, 32), blk, 0, stream>>>(
      kv_d, wbuf + 4194304, biasbuf + 2048, kb, vt, qb, ropetb, 512);

  flash_mfma_kernel<<<dim3(512), blk, 0, stream>>>(qb, kb, vt, attn);

  // output projection (narrow tile, fp32 out)
  gemm_bf16_n64<0, float><<<dim3(32, 32), blk, 0, stream>>>(
      attn, wbuf + 6815744, bo, (float*)d_out, nullptr, ropetb, 2048);
}

// Round 24
// 265.855 us; speedup vs baseline: 1.0464x; 1.0464x over previous
//
#include <hip/hip_runtime.h>
#include <cmath>

typedef unsigned short ushort_t;
typedef unsigned int u32;
typedef __attribute__((ext_vector_type(8))) __bf16 bf16x8;
typedef __attribute__((ext_vector_type(4))) float f32x4;

#define Hh 16
#define Ss 2048
#define SCALE 0.08838834764831845f

__device__ __forceinline__ ushort_t f2bf(float f) {
  union { float f; unsigned u; } c; c.f = f;
  unsigned u = c.u;
  return (ushort_t)((u + 0x7FFFu + ((u >> 16) & 1u)) >> 16);  // RNE
}
__device__ __forceinline__ float bf2f(ushort_t h) {
  union { unsigned u; float f; } c; c.u = ((unsigned)h) << 16;
  return c.f;
}
// pack 2 f32 -> 2 bf16 in one dword (lo->low16, hi->high16)
__device__ __forceinline__ u32 cvt_pk_bf16(float lo, float hi) {
  u32 r;
  asm volatile("v_cvt_pk_bf16_f32 %0, %1, %2" : "=v"(r) : "v"(lo), "v"(hi));
  return r;
}

// async global->LDS 16B (wave-uniform LDS base + lane*16B dest; per-lane gsrc)
__device__ __forceinline__ void gload_lds16(const ushort_t* g, ushort_t* l) {
  __builtin_amdgcn_global_load_lds(
      (const __attribute__((address_space(1))) u32*)g,
      (__attribute__((address_space(3))) u32*)l, 16, 0, 0);
}

// ---------------------------------------------------------------------------
// One-shot setup: segments 0..8 fp32->bf16 (x + 8 weights), 9..15 bias
// copies (fp32), 16 rope cos/sin table (65536 entries).
// ---------------------------------------------------------------------------
struct SrcPtrs { const float* p[16]; };

__global__ __launch_bounds__(256) void convert_all_kernel(SrcPtrs sp,
    ushort_t* __restrict__ x_bf, ushort_t* __restrict__ wbuf,
    float* __restrict__ biasbuf, float2* __restrict__ ropetb) {
  const int cum[16] = {8192, 9216, 10240, 12288, 12800, 13824, 14336, 14848,
                       18944, 18945, 18946, 18947, 18948, 18950, 18951, 18952};
  const int dsto[9] = {0, 0, 1048576, 2097152, 4194304, 4718592, 5767168, 6291456, 6815744};
  const int boff[7] = {0, 512, 1024, 2048, 3072, 5120, 6144};
  const int bsz[7]  = {512, 512, 1024, 1024, 2048, 1024, 1024};
  const int bid = blockIdx.x;
  int s = 0;
  #pragma unroll
  for (int i = 0; i < 16; ++i) s += (bid >= cum[i]);
  const int lb = bid - (s == 0 ? 0 : cum[s - 1]);
  if (s < 9) {
    const float* src = sp.p[s] + (size_t)lb * 1024;
    ushort_t* dst = (s == 0 ? x_bf : wbuf + dsto[s]) + (size_t)lb * 1024;
    const int i = threadIdx.x * 4;
    float4 v = *(const float4*)&src[i];
    ushort4 o;
    o.x = f2bf(v.x); o.y = f2bf(v.y); o.z = f2bf(v.z); o.w = f2bf(v.w);
    *(ushort4*)&dst[i] = o;
  } else if (s < 16) {
    const int k = s - 9;
    const int e = lb * 1024 + threadIdx.x * 4;
    if (e < bsz[k])
      *(float4*)&biasbuf[boff[k] + e] = *(const float4*)&sp.p[s][e];
  } else {
    const int i = lb * 256 + threadIdx.x;          // 65536 entries
    const int sq = i >> 5, ii = i & 31;
    const float invf = expf(-logf(10000.f) * (float)ii / 32.f);
    const float fr = (float)sq * invf;
    ropetb[i] = make_float2(cosf(fr), sinf(fr));
  }
}

// ---------------------------------------------------------------------------
// bf16 MFMA GEMM: 128x128 tile, BK=64, 4 waves, staging via global_load_lds
// x16 into LINEAR As/Bs[128][64]. Fused-output MODEs (block-uniform regions):
// MODE 0: out-proj fp32: addr = m*2048 + n
// MODE 2: x-fused  (N=2048): bx<8 -> kv_d/q_d (C0); bx>=8 -> kr+RoPE -> C1
// MODE 5: kvq-fused (N=5120): bx<8 -> kb (C0); bx<24 -> vt (C1);
//         bx<32 -> qb q1 (C2); bx>=32 -> qr+RoPE -> C2 (+64)
//         A = kv_d for bx<24 else q_d (= kv_d + 2097152)
// RoPE in-epilogue: thread holds both elements of each rotation pair.
// Tile-structure optimum confirmed from both sides: 128x64 (R23) and
// KVBLK-style growth (R19) both regressed.
// ---------------------------------------------------------------------------
template<int MODE, typename OUTT>
__global__ __launch_bounds__(256) void gemm_bf16(
    const ushort_t* __restrict__ A, const ushort_t* __restrict__ W,
    const float* __restrict__ bias, OUTT* __restrict__ C0,
    ushort_t* __restrict__ C1, ushort_t* __restrict__ C2,
    const float2* __restrict__ tb, int K)
{
  __shared__ ushort_t As[128][64];
  __shared__ ushort_t Bs[128][64];
  const int tid = threadIdx.x;
  const int lane = tid & 63;
  const int w = tid >> 6;
  const int wr = w >> 1, wc = w & 1;
  const int l15 = lane & 15, lhi = lane >> 4;
  const int m0 = blockIdx.y * 128, n0 = blockIdx.x * 128;

  if constexpr (MODE == 5) { if (blockIdx.x >= 24) A += 2097152; }

  const int srow_base = w * 8 + (lane >> 3);
  const int scol = (lane & 7) * 8;

  f32x4 acc[4][4];
  #pragma unroll
  for (int i = 0; i < 4; ++i)
    #pragma unroll
    for (int j = 0; j < 4; ++j)
      acc[i][j] = (f32x4){0.f, 0.f, 0.f, 0.f};

  for (int k0 = 0; k0 < K; k0 += 64) {
    __syncthreads();
    #pragma unroll
    for (int q = 0; q < 4; ++q) {
      const int row = q * 32 + srow_base;
      gload_lds16(&A[(size_t)(m0 + row) * K + k0 + scol], &As[q * 32 + w * 8][0]);
      gload_lds16(&W[(size_t)(n0 + row) * K + k0 + scol], &Bs[q * 32 + w * 8][0]);
    }
    __syncthreads();
    #pragma unroll
    for (int dk = 0; dk < 2; ++dk) {
      bf16x8 af[4], bfr[4];
      #pragma unroll
      for (int i = 0; i < 4; ++i)
        af[i] = *(const bf16x8*)&As[wr * 64 + i * 16 + l15][dk * 32 + lhi * 8];
      #pragma unroll
      for (int j = 0; j < 4; ++j)
        bfr[j] = *(const bf16x8*)&Bs[wc * 64 + j * 16 + l15][dk * 32 + lhi * 8];
      #pragma unroll
      for (int i = 0; i < 4; ++i)
        #pragma unroll
        for (int j = 0; j < 4; ++j)
          acc[i][j] = __builtin_amdgcn_mfma_f32_16x16x32_bf16(af[i], bfr[j], acc[i][j], 0, 0, 0);
    }
  }

  const bool rope_region =
      (MODE == 2 && blockIdx.x >= 8) || (MODE == 5 && blockIdx.x >= 32);

  if (rope_region) {
    #pragma unroll
    for (int i = 0; i < 4; ++i) {
      #pragma unroll
      for (int p = 0; p < 2; ++p) {
        const int nA = n0 + wc * 64 + p * 16 + l15;
        const int nB = nA + 32;
        const float bzA = bias[nA];
        const float bzB = bias[nB];
        int colA, colB;
        ushort_t* Cb;
        if constexpr (MODE == 2) {
          const int npA = nA - 1024;
          colA = (npA >> 6) * 128 + (npA & 63);
          colB = colA + 32;
          Cb = C1;                       // kb + 64 base
        } else {
          const int npA = nA - 4096;
          colA = (npA >> 6) * 128 + 64 + (npA & 63);
          colB = colA + 32;
          Cb = C2;                       // qb base
        }
        const int ii = p * 16 + l15;
        #pragma unroll
        for (int r = 0; r < 4; ++r) {
          const int m = m0 + wr * 64 + i * 16 + lhi * 4 + r;
          const int s = m & (Ss - 1);
          const float2 cs = tb[(s << 5) + ii];
          const float x1 = acc[i][p][r] + bzA;
          const float x2 = acc[i][p + 2][r] + bzB;
          Cb[(size_t)m * 2048 + colA] = f2bf(x1 * cs.x - x2 * cs.y);
          Cb[(size_t)m * 2048 + colB] = f2bf(x2 * cs.x + x1 * cs.y);
        }
      }
    }
    return;
  }

  #pragma unroll
  for (int i = 0; i < 4; ++i) {
    #pragma unroll
    for (int j = 0; j < 4; ++j) {
      const int n = n0 + wc * 64 + j * 16 + l15;
      const float bz = bias[n];
      #pragma unroll
      for (int r = 0; r < 4; ++r) {
        const int m = m0 + wr * 64 + i * 16 + lhi * 4 + r;
        const float v = acc[i][j][r] + bz;
        if constexpr (MODE == 0) {
          C0[(size_t)m * 2048 + n] = v;
        } else if constexpr (MODE == 2) {
          C0[(size_t)(n >> 9) * 2097152 + (size_t)m * 512 + (n & 511)] = (OUTT)f2bf(v);
        } else {  // MODE 5, bx<32
          if (n < 1024) {
            C0[(size_t)m * 2048 + (n >> 6) * 128 + (n & 63)] = (OUTT)f2bf(v);
          } else if (n < 3072) {
            const int np = n - 1024;
            C1[(size_t)(m >> 11) * 4194304 + (size_t)np * 2048 + (m & 2047)] = f2bf(v);
          } else {
            const int np = n - 3072;     // [0,1024): q1
            C2[(size_t)m * 2048 + (np >> 6) * 128 + (np & 63)] = f2bf(v);
          }
        }
      }
    }
  }
}

// ---------------------------------------------------------------------------
// MFMA flash attention (five-times-validated optimum): XOR-swizzled 48KB
// LDS, lazy softmax, swapped QK^T, reg prefetch of t+1 under compute,
// XCD-grouped blocks (K/V L2-resident: FETCH 139->24.7MB). 4 waves x 32
// q-rows, KVBLK=64. Plateau: ~172 total regs => 2 blocks/CU structural.
// Probed and rejected: KVBLK=128 (R19), split grid (R16), launch_bounds
// (R17 spill), setprio (R14), 8wx16 (R10), permlane P (R9), dbuf LDS (R8).
// ---------------------------------------------------------------------------
__global__ __launch_bounds__(256) void flash_mfma_kernel(
    const ushort_t* __restrict__ Qb, const ushort_t* __restrict__ Kb,
    const ushort_t* __restrict__ Vt, ushort_t* __restrict__ Oattn)
{
  __shared__ ushort_t Ks[64][128];     // [kk][d], XOR-swizzled chunks
  __shared__ ushort_t Vs[128][64];     // [d][kk], XOR-swizzled
  __shared__ ushort_t Ps[4][32][64];   // per-wave P tile [q][kk], XOR-swizzled

  const int tid = threadIdx.x, lane = tid & 63, w = tid >> 6;
  const int l15 = lane & 15, lhi = lane >> 4;
  const int l7 = l15 & 7;
  // XCD-grouped decode: id = xcd + 8*((bh/8)*16 + qx)
  const int id = blockIdx.x;
  const int xcd = id & 7, chunk = id >> 3;
  const int qx = chunk & 15, bh = ((chunk >> 4) << 3) | xcd;
  const int b = bh >> 4, h = bh & 15;
  const int q0 = qx * 128 + w * 32;

  // Q fragments (B-operand of swapped QK^T)
  bf16x8 qf[2][4];
  #pragma unroll
  for (int mi = 0; mi < 2; ++mi) {
    const size_t qrow = (size_t)b * Ss + q0 + mi * 16 + l15;
    const ushort_t* qp = Qb + (qrow * Hh + h) * 128;
    #pragma unroll
    for (int dk = 0; dk < 4; ++dk)
      qf[mi][dk] = *(const bf16x8*)(qp + dk * 32 + lhi * 8);
  }

  f32x4 o[2][8];
  #pragma unroll
  for (int mi = 0; mi < 2; ++mi)
    #pragma unroll
    for (int dn = 0; dn < 8; ++dn) o[mi][dn] = (f32x4){0.f, 0.f, 0.f, 0.f};
  float lsum[2] = {0.f, 0.f};

  const size_t kbase_g = (size_t)b * Ss * 2048 + (size_t)h * 128;
  const size_t vbase_g = (size_t)bh * 128 * Ss;

  // staging regs: tile t+1 loaded right after barrier 2 (hides under compute)
  bf16x8 kv[4], vv[4];
  #pragma unroll
  for (int p = 0; p < 4; ++p) {
    const int idx = p * 256 + tid;
    kv[p] = *(const bf16x8*)&Kb[kbase_g + (size_t)(idx >> 4) * 2048 + (idx & 15) * 8];
    vv[p] = *(const bf16x8*)&Vt[vbase_g + (size_t)(idx >> 3) * Ss + (idx & 7) * 8];
  }

  for (int t = 0; t < Ss / 64; ++t) {
    __syncthreads();   // previous iter's LDS readers done
    #pragma unroll
    for (int p = 0; p < 4; ++p) {
      const int idx = p * 256 + tid;
      const int kr = idx >> 4, kc = idx & 15;
      const int vr = idx >> 3, vc = idx & 7;
      *(bf16x8*)&Ks[kr][(kc ^ (kr & 7)) * 8] = kv[p];
      *(bf16x8*)&Vs[vr][(vc ^ (vr & 7)) * 8] = vv[p];
    }
    __syncthreads();

    // prefetch tile t+1 into regs; returns while we compute tile t
    if (t + 1 < Ss / 64) {
      const int s1 = (t + 1) * 64;
      #pragma unroll
      for (int p = 0; p < 4; ++p) {
        const int idx = p * 256 + tid;
        kv[p] = *(const bf16x8*)&Kb[kbase_g + (size_t)(s1 + (idx >> 4)) * 2048 + (idx & 15) * 8];
        vv[p] = *(const bf16x8*)&Vt[vbase_g + (size_t)(idx >> 3) * Ss + s1 + (idx & 7) * 8];
      }
    }

    // swapped QK^T: lane -> q = l15, kk = jc*16 + lhi*4 + r
    f32x4 s[2][4];
    #pragma unroll
    for (int mi = 0; mi < 2; ++mi)
      #pragma unroll
      for (int jc = 0; jc < 4; ++jc) s[mi][jc] = (f32x4){0.f, 0.f, 0.f, 0.f};
    #pragma unroll
    for (int jc = 0; jc < 4; ++jc)
      #pragma unroll
      for (int dk = 0; dk < 4; ++dk) {
        bf16x8 ak = *(const bf16x8*)&Ks[jc * 16 + l15][((dk * 4 + lhi) ^ l7) * 8];
        s[0][jc] = __builtin_amdgcn_mfma_f32_16x16x32_bf16(ak, qf[0][dk], s[0][jc], 0, 0, 0);
        s[1][jc] = __builtin_amdgcn_mfma_f32_16x16x32_bf16(ak, qf[1][dk], s[1][jc], 0, 0, 0);
      }

    // lazy softmax: p = exp(S*scale); lane-local sum (q = l15); packed b64
    // P-writes into swizzled Ps (16B chunk = 2jc+(lhi>>1), 8B half = lhi&1)
    #pragma unroll
    for (int mi = 0; mi < 2; ++mi)
      #pragma unroll
      for (int jc = 0; jc < 4; ++jc) {
        const float p0 = __expf(s[mi][jc][0] * SCALE);
        const float p1 = __expf(s[mi][jc][1] * SCALE);
        const float p2 = __expf(s[mi][jc][2] * SCALE);
        const float p3 = __expf(s[mi][jc][3] * SCALE);
        lsum[mi] += (p0 + p1) + (p2 + p3);
        const u32 d0 = cvt_pk_bf16(p0, p1);
        const u32 d1 = cvt_pk_bf16(p2, p3);
        const int ch = (jc * 2 + (lhi >> 1)) ^ l7;
        *(uint2*)&Ps[w][mi * 16 + l15][ch * 8 + (lhi & 1) * 4] = make_uint2(d0, d1);
      }

    // PV: A = P (q x kk), B = V chunk from Vs[d][kk]; 2 k-chunks of 32
    #pragma unroll
    for (int kc = 0; kc < 2; ++kc) {
      bf16x8 ap0 = *(const bf16x8*)&Ps[w][l15][((kc * 4 + lhi) ^ l7) * 8];
      bf16x8 ap1 = *(const bf16x8*)&Ps[w][16 + l15][((kc * 4 + lhi) ^ l7) * 8];
      #pragma unroll
      for (int dn = 0; dn < 8; ++dn) {
        bf16x8 bv = *(const bf16x8*)&Vs[dn * 16 + l15][((kc * 4 + lhi) ^ l7) * 8];
        o[0][dn] = __builtin_amdgcn_mfma_f32_16x16x32_bf16(ap0, bv, o[0][dn], 0, 0, 0);
        o[1][dn] = __builtin_amdgcn_mfma_f32_16x16x32_bf16(ap1, bv, o[1][dn], 0, 0, 0);
      }
    }
  }

  // final row-sum reduce across lhi groups: all lanes get total for q = l15
  #pragma unroll
  for (int mi = 0; mi < 2; ++mi) {
    float v = lsum[mi];
    v += __shfl_xor(v, 16);
    v += __shfl_xor(v, 32);
    lsum[mi] = v;
  }

  // epilogue: normalize (row totals via shfl), write (b,s,h,128) bf16
  #pragma unroll
  for (int mi = 0; mi < 2; ++mi) {
    float inv[4];
    #pragma unroll
    for (int r = 0; r < 4; ++r)
      inv[r] = 1.f / __shfl(lsum[mi], lhi * 4 + r);
    #pragma unroll
    for (int dn = 0; dn < 8; ++dn)
      #pragma unroll
      for (int r = 0; r < 4; ++r) {
        const int row = q0 + mi * 16 + lhi * 4 + r;
        const size_t addr = ((size_t)b * Ss + row) * 2048 + h * 128 + dn * 16 + l15;
        Oattn[addr] = f2bf(o[mi][dn][r] * inv[r]);
      }
  }
}

// ---------------------------------------------------------------------------
extern "C" void kernel_launch(void* const* d_in, const int* in_sizes, int n_in,
                              void* d_out, int out_size, void* d_ws, size_t ws_size,
                              hipStream_t stream)
{
  const float* x     = (const float*)d_in[0];
  const float* Wkv_d = (const float*)d_in[1];
  const float* bkv_d = (const float*)d_in[2];
  const float* Wq_d  = (const float*)d_in[3];
  const float* bq_d  = (const float*)d_in[4];
  const float* Wk_u  = (const float*)d_in[5];
  const float* bk_u  = (const float*)d_in[6];
  const float* Wq_u  = (const float*)d_in[7];
  const float* bq_u  = (const float*)d_in[8];
  const float* Wv_u  = (const float*)d_in[9];
  const float* bv_u  = (const float*)d_in[10];
  const float* Wrk   = (const float*)d_in[11];
  const float* brk   = (const float*)d_in[12];
  const float* Wrq   = (const float*)d_in[13];
  const float* brq   = (const float*)d_in[14];
  const float* Wo    = (const float*)d_in[15];
  const float* bo    = (const float*)d_in[16];

  ushort_t* ws = (ushort_t*)d_ws;
  ushort_t* x_bf  = ws;                       // [0, 8388608)
  ushort_t* kv_d  = ws + 8388608;             // [4096][512]
  ushort_t* q_d   = ws + 10485760;            // [4096][512] = kv_d + 2097152
  ushort_t* qb    = ws + 12582912;            // (b,s,h,128)
  ushort_t* kb    = ws + 20971520;
  ushort_t* vt    = ws + 29360128;            // [b][h][d][s]
  ushort_t* attn  = ws + 37748736;
  ushort_t* wbuf  = ws + 46137344;            // bf16 weights (11,010,048)
  float* biasbuf  = (float*)(ws + 57147392);  // 7168 f32
  float2* ropetb  = (float2*)(ws + 57161728); // 65536 float2 = 512 KB

  SrcPtrs sp;
  sp.p[0] = x;     sp.p[1] = Wkv_d; sp.p[2] = Wq_d;  sp.p[3] = Wrk;
  sp.p[4] = Wk_u;  sp.p[5] = Wv_u;  sp.p[6] = Wq_u;  sp.p[7] = Wrq;
  sp.p[8] = Wo;
  sp.p[9] = bkv_d; sp.p[10] = bq_d; sp.p[11] = brk;  sp.p[12] = bk_u;
  sp.p[13] = bv_u; sp.p[14] = bq_u; sp.p[15] = brq;
  convert_all_kernel<<<dim3(19208), dim3(256), 0, stream>>>(sp, x_bf, wbuf, biasbuf, ropetb);

  const dim3 blk(256);

  // x-fused: kv_d, q_d (bx<8); kr+RoPE -> kb+64 (bx>=8). N=2048, K=2048.
  gemm_bf16<2, ushort_t><<<dim3(16, 32), blk, 0, stream>>>(
      x_bf, wbuf, biasbuf, kv_d, kb + 64, nullptr, ropetb, 2048);
  // kvq-fused: k1 -> kb, V -> vt, q1 -> qb, qr+RoPE -> qb+64. N=5120, K=512.
  gemm_bf16<5, ushort_t><<<dim3(40, 32), blk, 0, stream>>>(
      kv_d, wbuf + 4194304, biasbuf + 2048, kb, vt, qb, ropetb, 512);

  flash_mfma_kernel<<<dim3(512), blk, 0, stream>>>(qb, kb, vt, attn);

  // output projection (fp32 out)
  gemm_bf16<0, float><<<dim3(16, 32), blk, 0, stream>>>(
      attn, wbuf + 6815744, bo, (float*)d_out, nullptr, nullptr, nullptr, 2048);
}